// Round 1
// baseline (295.163 us; speedup 1.0000x reference)
//
#include <hip/hip_runtime.h>
#include <stdint.h>

typedef __attribute__((ext_vector_type(8))) short s16x8;
typedef __attribute__((ext_vector_type(4))) float f32x4;

#define T_   2048
#define NH   16
#define HD   64
#define DIN  1024

// RTNE fp32 -> bf16
__device__ __forceinline__ unsigned short f2bf(float f) {
  union { float f; uint32_t u; } c; c.f = f;
  uint32_t u = c.u;
  return (unsigned short)((u + 0x7FFFu + ((u >> 16) & 1u)) >> 16);
}

// async global->LDS, 16B per lane; lds dest is wave-uniform base + lane*16
#define GLL(gp, lp) __builtin_amdgcn_global_load_lds( \
    (__attribute__((address_space(1))) void*)(gp),    \
    (__attribute__((address_space(3))) void*)(lp), 16, 0, 0)

// ---------------- kernel 1: fp32 -> bf16 conversion ----------------
// x: 4194304 elems -> xb ; Wq/Wk/Wv: 1048576 each -> wb (concatenated)
__global__ __launch_bounds__(256) void cvt_kernel(
    const float* __restrict__ x,  const float* __restrict__ wq,
    const float* __restrict__ wk, const float* __restrict__ wv,
    unsigned short* __restrict__ xb, unsigned short* __restrict__ wb) {
  int i = (blockIdx.x * 256 + threadIdx.x) * 4;
  float4 v;
  unsigned short* dp;
  if (i < 4194304) {
    v = *(const float4*)(x + i);
    dp = xb + i;
  } else {
    int j = i - 4194304;
    int seg = j >> 20, r = j & 1048575;
    const float* w = (seg == 0) ? wq : (seg == 1) ? wk : wv;
    v = *(const float4*)(w + r);
    dp = wb + j;
  }
  ushort4 o;
  o.x = f2bf(v.x); o.y = f2bf(v.y); o.z = f2bf(v.z); o.w = f2bf(v.w);
  *(ushort4*)dp = o;
}

// ---------------- kernel 2: QKV projection GEMM ----------------
// C[m=bt][n<3072] = sum_k X[m][k] * W[n][k]  (both bf16, K-major)
// Epilogue writes bf16 into qkv[sel][b][h][t][64].
__global__ __launch_bounds__(256) void qkv_gemm(
    const unsigned short* __restrict__ A, const unsigned short* __restrict__ Bm,
    unsigned short* __restrict__ qkv) {
  __shared__ __attribute__((aligned(16))) unsigned short Alds[128 * 64];
  __shared__ __attribute__((aligned(16))) unsigned short Blds[128 * 64];
  const int tid = threadIdx.x;
  const int lane = tid & 63, wave = tid >> 6;
  const int wm = wave >> 1, wn = wave & 1;
  const int m0 = blockIdx.y * 128, n0 = blockIdx.x * 128;

  f32x4 acc[4][4] = {};

  const int srow = wave * 32 + (lane >> 3);
  const int scol = (lane & 7) * 8;
  const unsigned short* ag = A  + (size_t)(m0 + srow) * DIN + scol;
  const unsigned short* bg = Bm + (size_t)(n0 + srow) * DIN + scol;
  unsigned short* al = &Alds[wave * 32 * 64];
  unsigned short* bl = &Blds[wave * 32 * 64];

  for (int k0 = 0; k0 < DIN; k0 += 64) {
    __syncthreads();
#pragma unroll
    for (int i = 0; i < 4; i++) {
      GLL(ag + (size_t)i * 8 * DIN + k0, al + i * 512);
      GLL(bg + (size_t)i * 8 * DIN + k0, bl + i * 512);
    }
    __syncthreads();
#pragma unroll
    for (int ks = 0; ks < 2; ks++) {
      s16x8 af[4], bf[4];
#pragma unroll
      for (int mt = 0; mt < 4; mt++)
        af[mt] = *(const s16x8*)&Alds[(wm * 64 + mt * 16 + (lane & 15)) * 64 + ks * 32 + (lane >> 4) * 8];
#pragma unroll
      for (int nt = 0; nt < 4; nt++)
        bf[nt] = *(const s16x8*)&Blds[(wn * 64 + nt * 16 + (lane & 15)) * 64 + ks * 32 + (lane >> 4) * 8];
#pragma unroll
      for (int mt = 0; mt < 4; mt++)
#pragma unroll
        for (int nt = 0; nt < 4; nt++)
          acc[mt][nt] = __builtin_amdgcn_mfma_f32_16x16x32_bf16(af[mt], bf[nt], acc[mt][nt], 0, 0, 0);
    }
  }

  // epilogue: C/D layout col=lane&15, row=(lane>>4)*4+r
#pragma unroll
  for (int mt = 0; mt < 4; mt++) {
    int mbase = m0 + wm * 64 + mt * 16 + ((lane >> 4) << 2);
#pragma unroll
    for (int nt = 0; nt < 4; nt++) {
      int n = n0 + wn * 64 + nt * 16 + (lane & 15);
      int sel = n >> 10, h = (n >> 6) & 15, d = n & 63;
#pragma unroll
      for (int r = 0; r < 4; r++) {
        int m = mbase + r;
        int b = m >> 11, t = m & 2047;
        qkv[(size_t)sel * 4194304 + ((size_t)((b * NH + h) * T_ + t) * HD) + d] =
            f2bf(acc[mt][nt][r]);
      }
    }
  }
}

// ---------------- kernel 3: causal flash attention ----------------
// grid (32 q-tiles, 32 bh). Block = 256 threads = 4 waves; wave w owns q rows
// [q0+16w, q0+16w+16). Output layout (faithful transpose):
// out[bh*131072 + d*2048 + s].
__global__ __launch_bounds__(256) void attn_kernel(
    const unsigned short* __restrict__ qkv, float* __restrict__ out) {
  __shared__ __attribute__((aligned(16))) unsigned short Klds[64 * 64];   // packed (global_load_lds)
  __shared__ __attribute__((aligned(16))) unsigned short Vt[64 * 72];     // V transposed, padded
  __shared__ __attribute__((aligned(16))) unsigned short Plds[4 * 16 * 72];
  __shared__ float Olds[64 * 65];

  const int lane = threadIdx.x & 63, wave = threadIdx.x >> 6;
  const int qt = blockIdx.x, bh = blockIdx.y;
  const int q0 = qt * 64;
  const size_t bh_off = (size_t)bh * T_ * HD;
  const unsigned short* Q = qkv;
  const unsigned short* K = qkv + 4194304;
  const unsigned short* V = qkv + 8388608;

  // Q fragments (A-operand layout: m=lane&15, k=(lane>>4)*8+j), loaded once
  s16x8 qf[2];
  {
    const unsigned short* qp =
        Q + bh_off + (size_t)(q0 + wave * 16 + (lane & 15)) * HD + (lane >> 4) * 8;
    qf[0] = *(const s16x8*)(qp);
    qf[1] = *(const s16x8*)(qp + 32);
  }

  const float scale_log2 = 0.125f * 1.4426950408889634f;  // (1/sqrt(64)) * log2(e)
  float m_r[4], l_r[4];
  f32x4 o[4] = {};
#pragma unroll
  for (int r = 0; r < 4; r++) { m_r[r] = -INFINITY; l_r[r] = 0.f; }

  unsigned short* pw = &Plds[wave * 16 * 72];

  for (int kt = 0; kt <= qt; kt++) {
    __syncthreads();
    // stage K tile (8KB contiguous): wave stages 16 rows via 2x 1KB issues
    {
      const unsigned short* kp = K + bh_off + (size_t)kt * 64 * HD + wave * 1024;
      unsigned short* kl = &Klds[wave * 1024];
      GLL(kp + lane * 8, kl);
      GLL(kp + 512 + lane * 8, kl + 512);
    }
    // stage V transposed: Vt[d][t_local], row stride 72
    {
      const unsigned short* vp = V + bh_off + (size_t)kt * 64 * HD;
      int tl = threadIdx.x >> 2;
      int ds = (threadIdx.x & 3) * 16;
      s16x8 v0 = *(const s16x8*)&vp[tl * 64 + ds];
      s16x8 v1 = *(const s16x8*)&vp[tl * 64 + ds + 8];
#pragma unroll
      for (int j = 0; j < 8; j++) {
        Vt[(ds + j) * 72 + tl]     = (unsigned short)v0[j];
        Vt[(ds + 8 + j) * 72 + tl] = (unsigned short)v1[j];
      }
    }
    __syncthreads();

    // S = Q @ K^T  (16 q-rows x 64 keys)
    f32x4 s[4] = {};
#pragma unroll
    for (int kk = 0; kk < 2; kk++)
#pragma unroll
      for (int nt = 0; nt < 4; nt++) {
        s16x8 kf = *(const s16x8*)&Klds[(nt * 16 + (lane & 15)) * 64 + kk * 32 + (lane >> 4) * 8];
        s[nt] = __builtin_amdgcn_mfma_f32_16x16x32_bf16(qf[kk], kf, s[nt], 0, 0, 0);
      }

    // scale to log2 domain + causal mask (mask-before-scale == same: -inf)
    float sv[4][4];
    const int row = q0 + wave * 16 + ((lane >> 4) << 2);
    const int col = kt * 64 + (lane & 15);
    const bool diag = (kt == qt);
#pragma unroll
    for (int nt = 0; nt < 4; nt++)
#pragma unroll
      for (int r = 0; r < 4; r++) {
        float v = s[nt][r] * scale_log2;
        if (diag && (col + nt * 16 > row + r)) v = -INFINITY;
        sv[nt][r] = v;
      }

    // row max across 64 keys: 4 frags + 16-lane butterfly
    float mx[4];
#pragma unroll
    for (int r = 0; r < 4; r++)
      mx[r] = fmaxf(fmaxf(sv[0][r], sv[1][r]), fmaxf(sv[2][r], sv[3][r]));
#pragma unroll
    for (int off = 1; off < 16; off <<= 1)
#pragma unroll
      for (int r = 0; r < 4; r++)
        mx[r] = fmaxf(mx[r], __shfl_xor(mx[r], off));

    // online softmax update
#pragma unroll
    for (int r = 0; r < 4; r++) {
      float mnew = fmaxf(m_r[r], mx[r]);
      float alpha = exp2f(m_r[r] - mnew);  // first iter: exp2(-inf)=0
      m_r[r] = mnew;
      l_r[r] *= alpha;
#pragma unroll
      for (int dt = 0; dt < 4; dt++) o[dt][r] *= alpha;
    }
    float p[4][4];
#pragma unroll
    for (int nt = 0; nt < 4; nt++)
#pragma unroll
      for (int r = 0; r < 4; r++)
        p[nt][r] = exp2f(sv[nt][r] - m_r[r]);  // masked -> 0
    float rs[4];
#pragma unroll
    for (int r = 0; r < 4; r++)
      rs[r] = (p[0][r] + p[1][r]) + (p[2][r] + p[3][r]);
#pragma unroll
    for (int off = 1; off < 16; off <<= 1)
#pragma unroll
      for (int r = 0; r < 4; r++)
        rs[r] += __shfl_xor(rs[r], off);
#pragma unroll
    for (int r = 0; r < 4; r++) l_r[r] += rs[r];

    // P (C-layout) -> per-wave LDS -> A-layout frags
#pragma unroll
    for (int nt = 0; nt < 4; nt++)
#pragma unroll
      for (int r = 0; r < 4; r++)
        pw[(((lane >> 4) << 2) + r) * 72 + nt * 16 + (lane & 15)] = f2bf(p[nt][r]);

    // O += P @ V   (B-frag from Vt: B[k=key][n=d] = Vt[d][key])
#pragma unroll
    for (int kk = 0; kk < 2; kk++) {
      s16x8 pf = *(const s16x8*)&pw[(lane & 15) * 72 + kk * 32 + (lane >> 4) * 8];
#pragma unroll
      for (int dt = 0; dt < 4; dt++) {
        s16x8 vf = *(const s16x8*)&Vt[(dt * 16 + (lane & 15)) * 72 + kk * 32 + (lane >> 4) * 8];
        o[dt] = __builtin_amdgcn_mfma_f32_16x16x32_bf16(pf, vf, o[dt], 0, 0, 0);
      }
    }
  }

  // normalize + transpose through LDS for the d-major output layout
#pragma unroll
  for (int r = 0; r < 4; r++) l_r[r] = 1.f / l_r[r];
#pragma unroll
  for (int dt = 0; dt < 4; dt++)
#pragma unroll
    for (int r = 0; r < 4; r++)
      Olds[(dt * 16 + (lane & 15)) * 65 + wave * 16 + ((lane >> 4) << 2) + r] =
          o[dt][r] * l_r[r];
  __syncthreads();
  {
    int d = threadIdx.x >> 2;
    int so = (threadIdx.x & 3) * 4;
    float* op = out + (size_t)bh * (HD * T_) + (size_t)d * T_ + q0;
#pragma unroll
    for (int j = 0; j < 4; j++) {
      int s = so + j * 16;
      float4 v = make_float4(Olds[d * 65 + s], Olds[d * 65 + s + 1],
                             Olds[d * 65 + s + 2], Olds[d * 65 + s + 3]);
      *(float4*)(op + s) = v;
    }
  }
}

extern "C" void kernel_launch(void* const* d_in, const int* in_sizes, int n_in,
                              void* d_out, int out_size, void* d_ws, size_t ws_size,
                              hipStream_t stream) {
  const float* x  = (const float*)d_in[0];
  const float* wq = (const float*)d_in[1];
  const float* wk = (const float*)d_in[2];
  const float* wv = (const float*)d_in[3];
  float* out = (float*)d_out;

  unsigned short* xb  = (unsigned short*)d_ws;       // 4194304 bf16
  unsigned short* wb  = xb + 4194304;                // 3145728 bf16 [Wq;Wk;Wv]
  unsigned short* qkv = wb + 3145728;                // 3 * 4194304 bf16

  cvt_kernel<<<7168, 256, 0, stream>>>(x, wq, wk, wv, xb, wb);
  dim3 g1(24, 32);  // N/128 x M/128
  qkv_gemm<<<g1, 256, 0, stream>>>(xb, wb, qkv);
  dim3 g2(32, 32);  // q-tiles x bh
  attn_kernel<<<g2, 256, 0, stream>>>(qkv, out);
}